// Round 6
// baseline (379.811 us; speedup 1.0000x reference)
//
#include <hip/hip_runtime.h>
#include <cmath>

#define HN 1024
#define NCH 12
#define PI2 6.28318530717958647692f

// ---------- complex helpers ----------
__device__ __forceinline__ float2 cmul(float2 a, float2 b) {
  return make_float2(a.x * b.x - a.y * b.y, a.x * b.y + a.y * b.x);
}

// reverse 5 base-4 digits of a 10-bit index (involution)
__device__ __forceinline__ int drev(int k) {
  int r = 0;
#pragma unroll
  for (int i = 0; i < 5; ++i) { r = (r << 2) | (k & 3); k >>= 2; }
  return r;
}

// row-kernel LDS swizzle: pad every 16 elements (uniform 4-way at all stages)
#define RIDX(h) ((h) + ((h) >> 4))
// padded twiddle index (kills same-bank broadcast serialization at e=16*m)
#define TIDX(i) ((i) + ((i) >> 4))
// column-exchange buffer: 512 rows x 16 cols, stride 17
#define EIDX(h, c) ((h) * 17 + (c))

// ---------- radix-4 DIF butterfly (row kernels, unpadded tw) ----------
template <bool INV>
__device__ __forceinline__ void bf4(float2& a0, float2& a1, float2& a2, float2& a3,
                                    const float2* tw, int e) {
  float2 t0 = make_float2(a0.x + a2.x, a0.y + a2.y);
  float2 t1 = make_float2(a0.x - a2.x, a0.y - a2.y);
  float2 t2 = make_float2(a1.x + a3.x, a1.y + a3.y);
  float2 t3 = make_float2(a1.x - a3.x, a1.y - a3.y);
  float2 b0 = make_float2(t0.x + t2.x, t0.y + t2.y);
  float2 b2 = make_float2(t0.x - t2.x, t0.y - t2.y);
  float2 b1, b3;
  if (!INV) {
    b1 = make_float2(t1.x + t3.y, t1.y - t3.x);
    b3 = make_float2(t1.x - t3.y, t1.y + t3.x);
  } else {
    b1 = make_float2(t1.x - t3.y, t1.y + t3.x);
    b3 = make_float2(t1.x + t3.y, t1.y - t3.x);
  }
  float2 w1 = tw[e], w2 = tw[2 * e], w3 = tw[3 * e];
  if (INV) { w1.y = -w1.y; w2.y = -w2.y; w3.y = -w3.y; }
  a0 = b0;
  a1 = cmul(b1, w1);
  a2 = cmul(b2, w2);
  a3 = cmul(b3, w3);
}

// ---------- radix-4 DIF butterfly (column kernels, TIDX-padded tw) ----------
template <bool INV>
__device__ __forceinline__ void bf4t(float2& a0, float2& a1, float2& a2, float2& a3,
                                     const float2* tw, int e) {
  float2 t0 = make_float2(a0.x + a2.x, a0.y + a2.y);
  float2 t1 = make_float2(a0.x - a2.x, a0.y - a2.y);
  float2 t2 = make_float2(a1.x + a3.x, a1.y + a3.y);
  float2 t3 = make_float2(a1.x - a3.x, a1.y - a3.y);
  float2 b0 = make_float2(t0.x + t2.x, t0.y + t2.y);
  float2 b2 = make_float2(t0.x - t2.x, t0.y - t2.y);
  float2 b1, b3;
  if (!INV) {
    b1 = make_float2(t1.x + t3.y, t1.y - t3.x);
    b3 = make_float2(t1.x - t3.y, t1.y + t3.x);
  } else {
    b1 = make_float2(t1.x - t3.y, t1.y + t3.x);
    b3 = make_float2(t1.x + t3.y, t1.y - t3.x);
  }
  float2 w1 = tw[TIDX(e)], w2 = tw[TIDX(2 * e)], w3 = tw[TIDX(3 * e)];
  if (INV) { w1.y = -w1.y; w2.y = -w2.y; w3.y = -w3.y; }
  a0 = b0;
  a1 = cmul(b1, w1);
  a2 = cmul(b2, w2);
  a3 = cmul(b3, w3);
}

__device__ __forceinline__ void tw_init(float2* tw, int t, int nthr) {
  for (int i = t; i < 768; i += nthr) {
    float s, c;
    sincosf((float)i * (PI2 / 1024.f), &s, &c);
    tw[i] = make_float2(c, -s);
  }
}

__device__ __forceinline__ void tw_init_p(float2* tw, int t, int nthr) {
  for (int i = t; i < 768; i += nthr) {
    float s, c;
    sincosf((float)i * (PI2 / 1024.f), &s, &c);
    tw[TIDX(i)] = make_float2(c, -s);
  }
}

// 1024-pt radix-4 DIF FFT, one row per block, 256 threads.
template <bool INV>
__device__ __forceinline__ void fft_row(float2* x, const float2* tw, int t) {
#pragma unroll
  for (int ld = 8; ld >= 0; ld -= 2) {
    __syncthreads();
    const int d = 1 << ld;
    int j = t & (d - 1);
    int p0 = ((t >> ld) << (ld + 2)) | j;
    float2 a0 = x[RIDX(p0)];
    float2 a1 = x[RIDX(p0 + d)];
    float2 a2 = x[RIDX(p0 + 2 * d)];
    float2 a3 = x[RIDX(p0 + 3 * d)];
    bf4<INV>(a0, a1, a2, a3, tw, j << (8 - ld));
    x[RIDX(p0)] = a0;
    x[RIDX(p0 + d)] = a1;
    x[RIDX(p0 + 2 * d)] = a2;
    x[RIDX(p0 + 3 * d)] = a3;
  }
  __syncthreads();
}

// ---------------------------------------------------------------------------
// Register-resident 1024-pt column FFT. 16 columns/block (c = t&15), 64
// threads per column (u = t>>4), 16 elements/thread: r[it] = x[u + 64*it].
// Stages d=256,d=64 thread-local; one half-buffer LDS exchange; stages
// d=16,d=4 thread-local; final d=1 stage via __shfl_xor (lane^32, lane^16).
// Output: q[m] holds the value whose standard DIF position is
//   p_std = 64*B + 16*(m>>2) + 4*(m&3) + bitrev2(j2).
// ---------------------------------------------------------------------------
template <bool INV>
__device__ __forceinline__ void colfft16(float2 (&r)[16], float2 (&q)[16],
                                         float2* ex, const float2* tw,
                                         int u, int c) {
  const int j2 = u & 3, B = u >> 2;
  // stage d=256
#pragma unroll
  for (int s = 0; s < 4; ++s)
    bf4t<INV>(r[s], r[s + 4], r[s + 8], r[s + 12], tw, u + (s << 6));
  // stage d=64
#pragma unroll
  for (int g = 0; g < 4; ++g)
    bf4t<INV>(r[4 * g], r[4 * g + 1], r[4 * g + 2], r[4 * g + 3], tw, u << 2);
  // exchange (half-tile, two phases)
#pragma unroll
  for (int it = 0; it < 8; ++it)
    ex[EIDX(u + (it << 6), c)] = r[it];
  __syncthreads();
  if (u < 32) {
#pragma unroll
    for (int m = 0; m < 16; ++m) {
      int hl = (B << 6) + j2 + ((m & 3) << 2) + ((m >> 2) << 4);
      q[m] = ex[EIDX(hl, c)];
    }
  }
  __syncthreads();
#pragma unroll
  for (int it = 8; it < 16; ++it)
    ex[EIDX(u + (it << 6) - 512, c)] = r[it];
  __syncthreads();
  if (u >= 32) {
#pragma unroll
    for (int m = 0; m < 16; ++m) {
      int hl = ((B - 8) << 6) + j2 + ((m & 3) << 2) + ((m >> 2) << 4);
      q[m] = ex[EIDX(hl, c)];
    }
  }
  // stage d=16
#pragma unroll
  for (int a = 0; a < 4; ++a)
    bf4t<INV>(q[a], q[4 + a], q[8 + a], q[12 + a], tw, (j2 + 4 * a) << 4);
  // stage d=4
#pragma unroll
  for (int b_ = 0; b_ < 4; ++b_)
    bf4t<INV>(q[4 * b_], q[4 * b_ + 1], q[4 * b_ + 2], q[4 * b_ + 3], tw, j2 << 6);
  // final stage d=1 across lanes j2 = (t>>4)&3: partners t^32 (j2 bit1), t^16 (j2 bit0)
#pragma unroll
  for (int m = 0; m < 16; ++m) {
    float2 v = q[m];
    float2 p;
    p.x = __shfl_xor(v.x, 32);
    p.y = __shfl_xor(v.y, 32);
    float2 w;
    if (j2 & 2) { w.x = p.x - v.x; w.y = p.y - v.y; }
    else        { w.x = v.x + p.x; w.y = v.y + p.y; }
    float2 p2;
    p2.x = __shfl_xor(w.x, 16);
    p2.y = __shfl_xor(w.y, 16);
    float2 o;
    if (j2 == 0)      { o = make_float2(w.x + p2.x, w.y + p2.y); }        // y0
    else if (j2 == 1) { o = make_float2(p2.x - w.x, p2.y - w.y); }        // y2
    else if (j2 == 2) { o = INV ? make_float2(w.x - p2.y, w.y + p2.x)     // y1
                                : make_float2(w.x + p2.y, w.y - p2.x); }
    else              { o = INV ? make_float2(p2.x + w.y, p2.y - w.x)     // y3
                                : make_float2(p2.x - w.y, p2.y + w.x); }
    q[m] = o;
  }
}

// ---------------- K1: row FFT of alpha*z -> A ; + F2k row-partial means -> S.zw ----------------
__global__ __launch_bounds__(256) void k1_rowfft(const float* __restrict__ z,
                                                 const float* __restrict__ alpha,
                                                 const float2* __restrict__ F2k,
                                                 float2* __restrict__ A,
                                                 float4* __restrict__ S) {
  __shared__ float2 x[1088];
  __shared__ float2 tw[768];
  const int t = threadIdx.x;
  const int row = blockIdx.x, nc = blockIdx.y;
  tw_init(tw, t, 256);
  const float al = alpha[nc / 3];
  const float* zr = z + ((size_t)nc * HN + row) * HN;
#pragma unroll
  for (int it = 0; it < 4; ++it) {
    int h = t + (it << 8);
    x[RIDX(h)] = make_float2(zr[h] * al, 0.f);
  }
  // invW partial: sum F2k over the 4 s2 column-groups of this row
  const float2* f2r = F2k + ((size_t)nc * HN + row) * HN;
  float sxr = 0.f, syr = 0.f;
#pragma unroll
  for (int it = 0; it < 4; ++it) {
    float2 v = f2r[t + (it << 8)];
    sxr += v.x; syr += v.y;
  }
  {
    float4* sp = S + (((size_t)nc << 16) | ((row & 255) << 8) | t);
    unsafeAtomicAdd(&sp->z, sxr);
    unsafeAtomicAdd(&sp->w, syr);
  }
  fft_row<false>(x, tw, t);
  float2* Ar = A + ((size_t)nc * HN + row) * HN;
#pragma unroll
  for (int it = 0; it < 4; ++it) {
    int k = t + (it << 8);
    Ar[k] = x[RIDX(drev(k))];
  }
}

// ---------------- K2: col FFT on A, +FkCFy -> FR; + FBR partial sums -> S.xy ----------------
__global__ __launch_bounds__(1024, 4) void k2_colfft(float2* __restrict__ A,
                                                     const float2* __restrict__ FkCFy,
                                                     const float2* __restrict__ Fk,
                                                     float4* __restrict__ S) {
  __shared__ float2 ex[8704];
  __shared__ float2 tw[816];
  const int t = threadIdx.x;
  const int c = t & 15, u = t >> 4;
  const int w0 = blockIdx.x << 4;
  const int nc = blockIdx.y;
  const size_t base = (size_t)nc * HN * HN + w0 + c;
  float2 r[16], q[16];
#pragma unroll
  for (int it = 0; it < 16; ++it)
    r[it] = A[base + (size_t)(u + (it << 6)) * HN];
  tw_init_p(tw, t, 1024);
  __syncthreads();
  colfft16<false>(r, q, ex, tw, u, c);
  const int j2 = u & 3, B = u >> 2;
  const int f = ((j2 & 1) << 1) | (j2 >> 1);
  const int jcol = (w0 + c) & 255;
  const size_t sbase = ((size_t)nc << 16) | jcol;
#pragma unroll
  for (int m = 0; m < 16; ++m) {
    int klo = ((m & 3) << 6) | ((m >> 2) << 4) | ((B & 3) << 2) | (B >> 2);
    int k = (f << 8) | klo;                    // klo == k & 255, same across j2 lanes
    size_t gi = base + (size_t)k * HN;
    float2 fy = FkCFy[gi];
    float2 fr = make_float2(q[m].x + fy.x, q[m].y + fy.y);
    A[gi] = fr;
    // FBR numerator partial: Fk*FR summed over the 4 s1 row-groups (= the 4 j2 lanes)
    float2 fk = Fk[gi];
    float2 pr = cmul(fk, fr);
    pr.x += __shfl_xor(pr.x, 16);
    pr.y += __shfl_xor(pr.y, 16);
    pr.x += __shfl_xor(pr.x, 32);
    pr.y += __shfl_xor(pr.y, 32);
    if (j2 == 0) {
      float4* sp = S + (sbase | (klo << 8));
      unsafeAtomicAdd(&sp->x, pr.x);
      unsafeAtomicAdd(&sp->y, pr.y);
    }
  }
}

// ---------------- K4: invWBR from S; FX = (FR - FkC*invWBR)/alpha; inverse col FFT ----------------
__global__ __launch_bounds__(1024, 4) void k4_colifft(float2* __restrict__ A,
                                                      const float2* __restrict__ FkC,
                                                      const float4* __restrict__ S,
                                                      const float* __restrict__ alpha) {
  __shared__ float2 ex[8704];
  __shared__ float2 tw[816];
  const int t = threadIdx.x;
  const int c = t & 15, u = t >> 4;
  const int w0 = blockIdx.x << 4;
  const int nc = blockIdx.y;
  const float al = alpha[nc / 3];
  const float ra = 1.0f / al;
  const size_t base = (size_t)nc * HN * HN + w0 + c;
  const int jcol = (w0 + c) & 255;
  const float4* Sp = S + ((size_t)nc << 16);
  float2 r[16], q[16];
#pragma unroll
  for (int it = 0; it < 16; ++it) {
    int h = u + (it << 6);
    size_t gi = base + (size_t)h * HN;
    float2 fr = A[gi];
    float2 fc = FkC[gi];
    float4 sv = Sp[((h & 255) << 8) | jcol];
    float dx = sv.z * 0.0625f + al, dy = sv.w * 0.0625f;   // invW + alpha
    float nx = sv.x * 0.0625f, ny = sv.y * 0.0625f;        // FBR
    float invd = 1.0f / (dx * dx + dy * dy);
    float2 w = make_float2((nx * dx + ny * dy) * invd, (ny * dx - nx * dy) * invd);
    float2 p = cmul(fc, w);
    r[it] = make_float2((fr.x - p.x) * ra, (fr.y - p.y) * ra);
  }
  tw_init_p(tw, t, 1024);
  __syncthreads();
  colfft16<true>(r, q, ex, tw, u, c);
  const int j2 = u & 3, B = u >> 2;
  const int f = ((j2 & 1) << 1) | (j2 >> 1);
#pragma unroll
  for (int m = 0; m < 16; ++m) {
    int k = (f << 8) | ((m & 3) << 6) | ((m >> 2) << 4) | ((B & 3) << 2) | (B >> 2);
    A[base + (size_t)k * HN] = q[m];
  }
}

// ---------------- K5: inverse row FFT -> real * 1/(H*W) -> out ----------------
__global__ __launch_bounds__(256) void k5_rowifft(const float2* __restrict__ A,
                                                  float* __restrict__ out) {
  __shared__ float2 x[1088];
  __shared__ float2 tw[768];
  const int t = threadIdx.x;
  const int row = blockIdx.x, nc = blockIdx.y;
  tw_init(tw, t, 256);
  const float2* Ar = A + ((size_t)nc * HN + row) * HN;
#pragma unroll
  for (int it = 0; it < 4; ++it) {
    int h = t + (it << 8);
    x[RIDX(h)] = Ar[h];
  }
  fft_row<true>(x, tw, t);
  float* outr = out + ((size_t)nc * HN + row) * HN;
  const float sc = 1.0f / (1024.0f * 1024.0f);
#pragma unroll
  for (int it = 0; it < 4; ++it) {
    int k = t + (it << 8);
    outr[k] = x[RIDX(drev(k))].x * sc;
  }
}

extern "C" void kernel_launch(void* const* d_in, const int* in_sizes, int n_in,
                              void* d_out, int out_size, void* d_ws, size_t ws_size,
                              hipStream_t stream) {
  const float*  z      = (const float*)d_in[0];
  const float2* Fk     = (const float2*)d_in[1];
  const float2* FkC    = (const float2*)d_in[2];
  const float2* F2k    = (const float2*)d_in[3];
  const float2* FkCFy  = (const float2*)d_in[4];
  const float*  alpha  = (const float*)d_in[5];
  (void)in_sizes; (void)n_in; (void)out_size; (void)ws_size;

  // workspace: A = 12 x 1024 x 1024 complex (96 MB), S = 12 x 256 x 256 float4 (12.6 MB)
  float2* A = (float2*)d_ws;
  float4* S = (float4*)((char*)d_ws + (size_t)NCH * HN * HN * sizeof(float2));
  float*  out = (float*)d_out;

  // zero the atomic sum buffer every call (replay-safe)
  hipMemsetAsync(S, 0, (size_t)NCH * 256 * 256 * sizeof(float4), stream);

  k1_rowfft<<<dim3(HN, NCH), dim3(256), 0, stream>>>(z, alpha, F2k, A, S);
  k2_colfft<<<dim3(HN / 16, NCH), dim3(1024), 0, stream>>>(A, FkCFy, Fk, S);
  k4_colifft<<<dim3(HN / 16, NCH), dim3(1024), 0, stream>>>(A, FkC, S, alpha);
  k5_rowifft<<<dim3(HN, NCH), dim3(256), 0, stream>>>(A, out);
}

// Round 7
// 349.517 us; speedup vs baseline: 1.0867x; 1.0867x over previous
//
#include <hip/hip_runtime.h>
#include <cmath>

#define HN 1024
#define NCH 12
#define PI2 6.28318530717958647692f

// ---------- complex helpers ----------
__device__ __forceinline__ float2 cmul(float2 a, float2 b) {
  return make_float2(a.x * b.x - a.y * b.y, a.x * b.y + a.y * b.x);
}

// padded twiddle index (kills same-bank broadcast serialization)
#define TIDX(i) ((i) + ((i) >> 4))
// column-exchange buffer: 512 rows x 16 cols, stride 17
#define EIDX(h, c) ((h) * 17 + (c))
// per-wave exchange buffer: pad every 16
#define WIDX(h) ((h) + ((h) >> 4))

// ---------- radix-4 DIF butterfly (TIDX-padded tw) ----------
template <bool INV>
__device__ __forceinline__ void bf4t(float2& a0, float2& a1, float2& a2, float2& a3,
                                     const float2* tw, int e) {
  float2 t0 = make_float2(a0.x + a2.x, a0.y + a2.y);
  float2 t1 = make_float2(a0.x - a2.x, a0.y - a2.y);
  float2 t2 = make_float2(a1.x + a3.x, a1.y + a3.y);
  float2 t3 = make_float2(a1.x - a3.x, a1.y - a3.y);
  float2 b0 = make_float2(t0.x + t2.x, t0.y + t2.y);
  float2 b2 = make_float2(t0.x - t2.x, t0.y - t2.y);
  float2 b1, b3;
  if (!INV) {
    b1 = make_float2(t1.x + t3.y, t1.y - t3.x);
    b3 = make_float2(t1.x - t3.y, t1.y + t3.x);
  } else {
    b1 = make_float2(t1.x - t3.y, t1.y + t3.x);
    b3 = make_float2(t1.x + t3.y, t1.y - t3.x);
  }
  float2 w1 = tw[TIDX(e)], w2 = tw[TIDX(2 * e)], w3 = tw[TIDX(3 * e)];
  if (INV) { w1.y = -w1.y; w2.y = -w2.y; w3.y = -w3.y; }
  a0 = b0;
  a1 = cmul(b1, w1);
  a2 = cmul(b2, w2);
  a3 = cmul(b3, w3);
}

__device__ __forceinline__ void tw_init_p(float2* tw, int t, int nthr) {
  for (int i = t; i < 768; i += nthr) {
    float s, c;
    sincosf((float)i * (PI2 / 1024.f), &s, &c);
    tw[TIDX(i)] = make_float2(c, -s);
  }
}

// ---------------------------------------------------------------------------
// Wave-private 1024-pt register FFT (one row per 64-lane wave, NO barriers).
// lane u holds r[it] = x[u + 64*it]. Stages d=256,d=64 thread-local; full
// per-wave LDS exchange; stages d=16,d=4 local; d=1 via shfl_xor(2),(1).
// Output q[m] sits at DIF position p_std = 64*B + 16*(m>>2) + 4*(m&3) + brev2(j2).
// ---------------------------------------------------------------------------
template <bool INV>
__device__ __forceinline__ void wavefft16(float2 (&r)[16], float2 (&q)[16],
                                          float2* ex, const float2* tw, int u) {
  const int j2 = u & 3, B = u >> 2;
#pragma unroll
  for (int s = 0; s < 4; ++s)
    bf4t<INV>(r[s], r[s + 4], r[s + 8], r[s + 12], tw, u + (s << 6));
#pragma unroll
  for (int g = 0; g < 4; ++g)
    bf4t<INV>(r[4 * g], r[4 * g + 1], r[4 * g + 2], r[4 * g + 3], tw, u << 2);
#pragma unroll
  for (int it = 0; it < 16; ++it)
    ex[WIDX(u + (it << 6))] = r[it];
  asm volatile("s_waitcnt lgkmcnt(0)" ::: "memory");
#pragma unroll
  for (int m = 0; m < 16; ++m)
    q[m] = ex[WIDX((B << 6) + j2 + ((m & 3) << 2) + ((m >> 2) << 4))];
#pragma unroll
  for (int a = 0; a < 4; ++a)
    bf4t<INV>(q[a], q[4 + a], q[8 + a], q[12 + a], tw, (j2 + 4 * a) << 4);
#pragma unroll
  for (int b_ = 0; b_ < 4; ++b_)
    bf4t<INV>(q[4 * b_], q[4 * b_ + 1], q[4 * b_ + 2], q[4 * b_ + 3], tw, j2 << 6);
  // d=1 stage: j2 bits live in lane bits [1:0] -> partners lane^2 then lane^1
#pragma unroll
  for (int m = 0; m < 16; ++m) {
    float2 v = q[m];
    float2 p;
    p.x = __shfl_xor(v.x, 2);
    p.y = __shfl_xor(v.y, 2);
    float2 w;
    if (j2 & 2) { w.x = p.x - v.x; w.y = p.y - v.y; }
    else        { w.x = v.x + p.x; w.y = v.y + p.y; }
    float2 p2;
    p2.x = __shfl_xor(w.x, 1);
    p2.y = __shfl_xor(w.y, 1);
    float2 o;
    if (j2 == 0)      { o = make_float2(w.x + p2.x, w.y + p2.y); }
    else if (j2 == 1) { o = make_float2(p2.x - w.x, p2.y - w.y); }
    else if (j2 == 2) { o = INV ? make_float2(w.x - p2.y, w.y + p2.x)
                                : make_float2(w.x + p2.y, w.y - p2.x); }
    else              { o = INV ? make_float2(p2.x + w.y, p2.y - w.x)
                                : make_float2(p2.x - w.y, p2.y + w.x); }
    q[m] = o;
  }
}

// ---------------------------------------------------------------------------
// Block-cooperative column FFT (16 columns, 1024 threads) — as R5.
// ---------------------------------------------------------------------------
template <bool INV>
__device__ __forceinline__ void colfft16(float2 (&r)[16], float2 (&q)[16],
                                         float2* ex, const float2* tw,
                                         int u, int c) {
  const int j2 = u & 3, B = u >> 2;
#pragma unroll
  for (int s = 0; s < 4; ++s)
    bf4t<INV>(r[s], r[s + 4], r[s + 8], r[s + 12], tw, u + (s << 6));
#pragma unroll
  for (int g = 0; g < 4; ++g)
    bf4t<INV>(r[4 * g], r[4 * g + 1], r[4 * g + 2], r[4 * g + 3], tw, u << 2);
#pragma unroll
  for (int it = 0; it < 8; ++it)
    ex[EIDX(u + (it << 6), c)] = r[it];
  __syncthreads();
  if (u < 32) {
#pragma unroll
    for (int m = 0; m < 16; ++m) {
      int hl = (B << 6) + j2 + ((m & 3) << 2) + ((m >> 2) << 4);
      q[m] = ex[EIDX(hl, c)];
    }
  }
  __syncthreads();
#pragma unroll
  for (int it = 8; it < 16; ++it)
    ex[EIDX(u + (it << 6) - 512, c)] = r[it];
  __syncthreads();
  if (u >= 32) {
#pragma unroll
    for (int m = 0; m < 16; ++m) {
      int hl = ((B - 8) << 6) + j2 + ((m & 3) << 2) + ((m >> 2) << 4);
      q[m] = ex[EIDX(hl, c)];
    }
  }
#pragma unroll
  for (int a = 0; a < 4; ++a)
    bf4t<INV>(q[a], q[4 + a], q[8 + a], q[12 + a], tw, (j2 + 4 * a) << 4);
#pragma unroll
  for (int b_ = 0; b_ < 4; ++b_)
    bf4t<INV>(q[4 * b_], q[4 * b_ + 1], q[4 * b_ + 2], q[4 * b_ + 3], tw, j2 << 6);
  // d=1 stage: j2 bits live in lane bits [5:4] -> partners lane^32 then lane^16
#pragma unroll
  for (int m = 0; m < 16; ++m) {
    float2 v = q[m];
    float2 p;
    p.x = __shfl_xor(v.x, 32);
    p.y = __shfl_xor(v.y, 32);
    float2 w;
    if (j2 & 2) { w.x = p.x - v.x; w.y = p.y - v.y; }
    else        { w.x = v.x + p.x; w.y = v.y + p.y; }
    float2 p2;
    p2.x = __shfl_xor(w.x, 16);
    p2.y = __shfl_xor(w.y, 16);
    float2 o;
    if (j2 == 0)      { o = make_float2(w.x + p2.x, w.y + p2.y); }
    else if (j2 == 1) { o = make_float2(p2.x - w.x, p2.y - w.y); }
    else if (j2 == 2) { o = INV ? make_float2(w.x - p2.y, w.y + p2.x)
                                : make_float2(w.x + p2.y, w.y - p2.x); }
    else              { o = INV ? make_float2(p2.x + w.y, p2.y - w.x)
                                : make_float2(p2.x - w.y, p2.y + w.x); }
    q[m] = o;
  }
}

// ---------------- K1: row FFT of alpha*z -> A (wave-per-row, barrier-free) ----------------
__global__ __launch_bounds__(512) void k1_rowfft(const float* __restrict__ z,
                                                 const float* __restrict__ alpha,
                                                 float2* __restrict__ A) {
  __shared__ float2 ex[8 * 1088];
  __shared__ float2 tw[816];
  const int t = threadIdx.x;
  const int w = t >> 6, u = t & 63;
  const int row = (blockIdx.x << 3) + w, nc = blockIdx.y;
  tw_init_p(tw, t, 512);
  __syncthreads();
  const float al = alpha[nc / 3];
  const float* zr = z + ((size_t)nc * HN + row) * HN;
  float2 r[16], q[16];
#pragma unroll
  for (int it = 0; it < 16; ++it)
    r[it] = make_float2(zr[u + (it << 6)] * al, 0.f);
  float2* exw = ex + w * 1088;
  wavefft16<false>(r, q, exw, tw, u);
  const int j2 = u & 3, B = u >> 2;
  const int f = ((j2 & 1) << 1) | (j2 >> 1);
  // scatter to freq-natural order in LDS, then coalesced store
#pragma unroll
  for (int m = 0; m < 16; ++m) {
    int k = (f << 8) | ((m & 3) << 6) | ((m >> 2) << 4) | ((B & 3) << 2) | (B >> 2);
    exw[WIDX(k)] = q[m];
  }
  asm volatile("s_waitcnt lgkmcnt(0)" ::: "memory");
  float2* Ar = A + ((size_t)nc * HN + row) * HN;
#pragma unroll
  for (int it = 0; it < 16; ++it) {
    int k = u + (it << 6);
    Ar[k] = exw[WIDX(k)];
  }
}

// ---------------- K2: col FFT in-place on A, + FkCFy -> FR ----------------
__global__ __launch_bounds__(1024, 4) void k2_colfft(float2* __restrict__ A,
                                                     const float2* __restrict__ FkCFy) {
  __shared__ float2 ex[8704];
  __shared__ float2 tw[816];
  const int t = threadIdx.x;
  const int c = t & 15, u = t >> 4;
  const int w0 = blockIdx.x << 4;
  const int nc = blockIdx.y;
  tw_init_p(tw, t, 1024);
  __syncthreads();
  const size_t base = (size_t)nc * HN * HN + w0 + c;
  const int j2 = u & 3, B = u >> 2;
  const int f = ((j2 & 1) << 1) | (j2 >> 1);
  float2 r[16], fy[16];
#pragma unroll
  for (int it = 0; it < 16; ++it)
    r[it] = A[base + (size_t)(u + (it << 6)) * HN];
  // prefetch epilogue operand now; latency hides under the FFT
#pragma unroll
  for (int m = 0; m < 16; ++m) {
    int k = (f << 8) | ((m & 3) << 6) | ((m >> 2) << 4) | ((B & 3) << 2) | (B >> 2);
    fy[m] = FkCFy[base + (size_t)k * HN];
  }
  float2 q[16];
  colfft16<false>(r, q, ex, tw, u, c);
#pragma unroll
  for (int m = 0; m < 16; ++m) {
    int k = (f << 8) | ((m & 3) << 6) | ((m >> 2) << 4) | ((B & 3) << 2) | (B >> 2);
    A[base + (size_t)k * HN] = make_float2(q[m].x + fy[m].x, q[m].y + fy[m].y);
  }
}

// ---------------- K3: fused block-means + complex divide -> invWBR ----------------
__global__ __launch_bounds__(256) void k3_reduce(const float2* __restrict__ A,
                                                 const float2* __restrict__ Fk,
                                                 const float2* __restrict__ F2k,
                                                 const float* __restrict__ alpha,
                                                 float2* __restrict__ iw) {
  int idx = blockIdx.x * 256 + threadIdx.x;
  int j = idx & 255, i = (idx >> 8) & 255, nc = idx >> 16;
  size_t base = (size_t)nc * HN * HN;
  float sx = 0.f, sy = 0.f, wx = 0.f, wy = 0.f;
#pragma unroll
  for (int s1 = 0; s1 < 4; ++s1) {
#pragma unroll
    for (int s2 = 0; s2 < 4; ++s2) {
      size_t gi = base + (size_t)((s1 << 8) + i) * HN + ((s2 << 8) + j);
      float2 fr = A[gi];
      float2 fk = Fk[gi];
      float2 f2 = F2k[gi];
      sx += fk.x * fr.x - fk.y * fr.y;
      sy += fk.x * fr.y + fk.y * fr.x;
      wx += f2.x;
      wy += f2.y;
    }
  }
  const float al = alpha[nc / 3];
  float dx = wx * 0.0625f + al, dy = wy * 0.0625f;
  float nx = sx * 0.0625f, ny = sy * 0.0625f;
  float inv = 1.0f / (dx * dx + dy * dy);
  iw[idx] = make_float2((nx * dx + ny * dy) * inv, (ny * dx - nx * dy) * inv);
}

// ---------------- K4: FX = (FR - FkC*invWBR)/alpha, inverse col FFT in-place ----------------
__global__ __launch_bounds__(1024, 4) void k4_colifft(float2* __restrict__ A,
                                                      const float2* __restrict__ FkC,
                                                      const float2* __restrict__ iw,
                                                      const float* __restrict__ alpha) {
  __shared__ float2 ex[8704];
  __shared__ float2 tw[816];
  const int t = threadIdx.x;
  const int c = t & 15, u = t >> 4;
  const int w0 = blockIdx.x << 4;
  const int nc = blockIdx.y;
  tw_init_p(tw, t, 1024);
  __syncthreads();
  const float al = alpha[nc / 3];
  const float ra = 1.0f / al;
  const size_t base = (size_t)nc * HN * HN + w0 + c;
  const int jcol = (w0 + c) & 255;
  const float2* iwp = iw + ((size_t)nc << 16);
  // hoist the 4 distinct invWBR values (h&255 = u + 64*(it&3))
  float2 wv[4];
#pragma unroll
  for (int s = 0; s < 4; ++s)
    wv[s] = iwp[((u + (s << 6)) << 8) | jcol];
  float2 r[16], q[16];
#pragma unroll
  for (int it = 0; it < 16; ++it) {
    int h = u + (it << 6);
    size_t gi = base + (size_t)h * HN;
    float2 fr = A[gi];
    float2 fc = FkC[gi];
    float2 p = cmul(fc, wv[it & 3]);
    r[it] = make_float2((fr.x - p.x) * ra, (fr.y - p.y) * ra);
  }
  colfft16<true>(r, q, ex, tw, u, c);
  const int j2 = u & 3, B = u >> 2;
  const int f = ((j2 & 1) << 1) | (j2 >> 1);
#pragma unroll
  for (int m = 0; m < 16; ++m) {
    int k = (f << 8) | ((m & 3) << 6) | ((m >> 2) << 4) | ((B & 3) << 2) | (B >> 2);
    A[base + (size_t)k * HN] = q[m];
  }
}

// ---------------- K5: inverse row FFT -> real * 1/(H*W) -> out (wave-per-row) ----------------
__global__ __launch_bounds__(512) void k5_rowifft(const float2* __restrict__ A,
                                                  float* __restrict__ out) {
  __shared__ float2 ex[8 * 1088];
  __shared__ float2 tw[816];
  const int t = threadIdx.x;
  const int w = t >> 6, u = t & 63;
  const int row = (blockIdx.x << 3) + w, nc = blockIdx.y;
  tw_init_p(tw, t, 512);
  __syncthreads();
  const float2* Ar = A + ((size_t)nc * HN + row) * HN;
  float2 r[16], q[16];
#pragma unroll
  for (int it = 0; it < 16; ++it)
    r[it] = Ar[u + (it << 6)];
  float2* exw = ex + w * 1088;
  wavefft16<true>(r, q, exw, tw, u);
  const int j2 = u & 3, B = u >> 2;
  const int f = ((j2 & 1) << 1) | (j2 >> 1);
#pragma unroll
  for (int m = 0; m < 16; ++m) {
    int k = (f << 8) | ((m & 3) << 6) | ((m >> 2) << 4) | ((B & 3) << 2) | (B >> 2);
    exw[WIDX(k)] = q[m];
  }
  asm volatile("s_waitcnt lgkmcnt(0)" ::: "memory");
  float* outr = out + ((size_t)nc * HN + row) * HN;
  const float sc = 1.0f / (1024.0f * 1024.0f);
#pragma unroll
  for (int it = 0; it < 16; ++it) {
    int k = u + (it << 6);
    outr[k] = exw[WIDX(k)].x * sc;
  }
}

extern "C" void kernel_launch(void* const* d_in, const int* in_sizes, int n_in,
                              void* d_out, int out_size, void* d_ws, size_t ws_size,
                              hipStream_t stream) {
  const float*  z      = (const float*)d_in[0];
  const float2* Fk     = (const float2*)d_in[1];
  const float2* FkC    = (const float2*)d_in[2];
  const float2* F2k    = (const float2*)d_in[3];
  const float2* FkCFy  = (const float2*)d_in[4];
  const float*  alpha  = (const float*)d_in[5];
  (void)in_sizes; (void)n_in; (void)out_size; (void)ws_size;

  float2* A  = (float2*)d_ws;                 // 12 x 1024 x 1024 complex (96 MB)
  float2* iw = A + (size_t)NCH * HN * HN;     // 12 x 256 x 256 complex (6 MB)
  float*  out = (float*)d_out;

  k1_rowfft<<<dim3(HN / 8, NCH), dim3(512), 0, stream>>>(z, alpha, A);
  k2_colfft<<<dim3(HN / 16, NCH), dim3(1024), 0, stream>>>(A, FkCFy);
  k3_reduce<<<dim3(NCH * 256), dim3(256), 0, stream>>>(A, Fk, F2k, alpha, iw);
  k4_colifft<<<dim3(HN / 16, NCH), dim3(1024), 0, stream>>>(A, FkC, iw, alpha);
  k5_rowifft<<<dim3(HN / 8, NCH), dim3(512), 0, stream>>>(A, out);
}

// Round 8
// 278.075 us; speedup vs baseline: 1.3659x; 1.2569x over previous
//
#include <hip/hip_runtime.h>
#include <cmath>

#define HN 1024
#define NCH 12
#define PI2 6.28318530717958647692f

// ---------- complex helpers ----------
__device__ __forceinline__ float2 cmul(float2 a, float2 b) {
  return make_float2(a.x * b.x - a.y * b.y, a.x * b.y + a.y * b.x);
}

// reverse 5 base-4 digits of a 10-bit index (involution)
__device__ __forceinline__ int drev(int k) {
  int r = 0;
#pragma unroll
  for (int i = 0; i < 5; ++i) { r = (r << 2) | (k & 3); k >>= 2; }
  return r;
}

// HBM channel swizzle for the A intermediate: cell (row h, col w) lives at
// physical col w ^ ((h&63)<<4). Spreads a column-tile's 1024 row-segments
// across 64 byte-offset bins (addr bits 7..12) instead of 1. Bijective per
// row; read-owner == write-owner for every cell (XOR depends only on h).
__device__ __forceinline__ int aswz(int h, int w) { return w ^ ((h & 63) << 4); }

// row-kernel LDS swizzle: pad every 16 elements (uniform 4-way at all stages)
#define RIDX(h) ((h) + ((h) >> 4))
// padded twiddle index (kills same-bank broadcast serialization)
#define TIDX(i) ((i) + ((i) >> 4))
// column-exchange buffer: 512 rows x 16 cols, stride 17
#define EIDX(h, c) ((h) * 17 + (c))

// ---------- radix-4 DIF butterfly (row kernels, unpadded tw) ----------
template <bool INV>
__device__ __forceinline__ void bf4(float2& a0, float2& a1, float2& a2, float2& a3,
                                    const float2* tw, int e) {
  float2 t0 = make_float2(a0.x + a2.x, a0.y + a2.y);
  float2 t1 = make_float2(a0.x - a2.x, a0.y - a2.y);
  float2 t2 = make_float2(a1.x + a3.x, a1.y + a3.y);
  float2 t3 = make_float2(a1.x - a3.x, a1.y - a3.y);
  float2 b0 = make_float2(t0.x + t2.x, t0.y + t2.y);
  float2 b2 = make_float2(t0.x - t2.x, t0.y - t2.y);
  float2 b1, b3;
  if (!INV) {
    b1 = make_float2(t1.x + t3.y, t1.y - t3.x);
    b3 = make_float2(t1.x - t3.y, t1.y + t3.x);
  } else {
    b1 = make_float2(t1.x - t3.y, t1.y + t3.x);
    b3 = make_float2(t1.x + t3.y, t1.y - t3.x);
  }
  float2 w1 = tw[e], w2 = tw[2 * e], w3 = tw[3 * e];
  if (INV) { w1.y = -w1.y; w2.y = -w2.y; w3.y = -w3.y; }
  a0 = b0;
  a1 = cmul(b1, w1);
  a2 = cmul(b2, w2);
  a3 = cmul(b3, w3);
}

// ---------- radix-4 DIF butterfly (column kernels, TIDX-padded tw) ----------
template <bool INV>
__device__ __forceinline__ void bf4t(float2& a0, float2& a1, float2& a2, float2& a3,
                                     const float2* tw, int e) {
  float2 t0 = make_float2(a0.x + a2.x, a0.y + a2.y);
  float2 t1 = make_float2(a0.x - a2.x, a0.y - a2.y);
  float2 t2 = make_float2(a1.x + a3.x, a1.y + a3.y);
  float2 t3 = make_float2(a1.x - a3.x, a1.y - a3.y);
  float2 b0 = make_float2(t0.x + t2.x, t0.y + t2.y);
  float2 b2 = make_float2(t0.x - t2.x, t0.y - t2.y);
  float2 b1, b3;
  if (!INV) {
    b1 = make_float2(t1.x + t3.y, t1.y - t3.x);
    b3 = make_float2(t1.x - t3.y, t1.y + t3.x);
  } else {
    b1 = make_float2(t1.x - t3.y, t1.y + t3.x);
    b3 = make_float2(t1.x + t3.y, t1.y - t3.x);
  }
  float2 w1 = tw[TIDX(e)], w2 = tw[TIDX(2 * e)], w3 = tw[TIDX(3 * e)];
  if (INV) { w1.y = -w1.y; w2.y = -w2.y; w3.y = -w3.y; }
  a0 = b0;
  a1 = cmul(b1, w1);
  a2 = cmul(b2, w2);
  a3 = cmul(b3, w3);
}

__device__ __forceinline__ void tw_init(float2* tw, int t, int nthr) {
  for (int i = t; i < 768; i += nthr) {
    float s, c;
    sincosf((float)i * (PI2 / 1024.f), &s, &c);
    tw[i] = make_float2(c, -s);
  }
}

__device__ __forceinline__ void tw_init_p(float2* tw, int t, int nthr) {
  for (int i = t; i < 768; i += nthr) {
    float s, c;
    sincosf((float)i * (PI2 / 1024.f), &s, &c);
    tw[TIDX(i)] = make_float2(c, -s);
  }
}

// 1024-pt radix-4 DIF FFT, one row per block, 256 threads.
template <bool INV>
__device__ __forceinline__ void fft_row(float2* x, const float2* tw, int t) {
#pragma unroll
  for (int ld = 8; ld >= 0; ld -= 2) {
    __syncthreads();
    const int d = 1 << ld;
    int j = t & (d - 1);
    int p0 = ((t >> ld) << (ld + 2)) | j;
    float2 a0 = x[RIDX(p0)];
    float2 a1 = x[RIDX(p0 + d)];
    float2 a2 = x[RIDX(p0 + 2 * d)];
    float2 a3 = x[RIDX(p0 + 3 * d)];
    bf4<INV>(a0, a1, a2, a3, tw, j << (8 - ld));
    x[RIDX(p0)] = a0;
    x[RIDX(p0 + d)] = a1;
    x[RIDX(p0 + 2 * d)] = a2;
    x[RIDX(p0 + 3 * d)] = a3;
  }
  __syncthreads();
}

// ---------------------------------------------------------------------------
// Register-resident 1024-pt column FFT. 16 columns/block (c = t&15), 64
// threads per column (u = t>>4), 16 elements/thread: r[it] = x[u + 64*it].
// Stages d=256,d=64 thread-local; one half-buffer LDS exchange; stages
// d=16,d=4 thread-local; final d=1 stage via __shfl_xor (lane^32, lane^16).
// Output: q[m] holds the value whose standard DIF position is
//   p_std = 64*B + 16*(m>>2) + 4*(m&3) + bitrev2(j2).
// ---------------------------------------------------------------------------
template <bool INV>
__device__ __forceinline__ void colfft16(float2 (&r)[16], float2 (&q)[16],
                                         float2* ex, const float2* tw,
                                         int u, int c) {
  const int j2 = u & 3, B = u >> 2;
  // stage d=256
#pragma unroll
  for (int s = 0; s < 4; ++s)
    bf4t<INV>(r[s], r[s + 4], r[s + 8], r[s + 12], tw, u + (s << 6));
  // stage d=64
#pragma unroll
  for (int g = 0; g < 4; ++g)
    bf4t<INV>(r[4 * g], r[4 * g + 1], r[4 * g + 2], r[4 * g + 3], tw, u << 2);
  // exchange (half-tile, two phases)
#pragma unroll
  for (int it = 0; it < 8; ++it)
    ex[EIDX(u + (it << 6), c)] = r[it];
  __syncthreads();
  if (u < 32) {
#pragma unroll
    for (int m = 0; m < 16; ++m) {
      int hl = (B << 6) + j2 + ((m & 3) << 2) + ((m >> 2) << 4);
      q[m] = ex[EIDX(hl, c)];
    }
  }
  __syncthreads();
#pragma unroll
  for (int it = 8; it < 16; ++it)
    ex[EIDX(u + (it << 6) - 512, c)] = r[it];
  __syncthreads();
  if (u >= 32) {
#pragma unroll
    for (int m = 0; m < 16; ++m) {
      int hl = ((B - 8) << 6) + j2 + ((m & 3) << 2) + ((m >> 2) << 4);
      q[m] = ex[EIDX(hl, c)];
    }
  }
  // stage d=16
#pragma unroll
  for (int a = 0; a < 4; ++a)
    bf4t<INV>(q[a], q[4 + a], q[8 + a], q[12 + a], tw, (j2 + 4 * a) << 4);
  // stage d=4
#pragma unroll
  for (int b_ = 0; b_ < 4; ++b_)
    bf4t<INV>(q[4 * b_], q[4 * b_ + 1], q[4 * b_ + 2], q[4 * b_ + 3], tw, j2 << 6);
  // final stage d=1 across lanes j2 = (t>>4)&3: partners t^32 then t^16
#pragma unroll
  for (int m = 0; m < 16; ++m) {
    float2 v = q[m];
    float2 p;
    p.x = __shfl_xor(v.x, 32);
    p.y = __shfl_xor(v.y, 32);
    float2 w;
    if (j2 & 2) { w.x = p.x - v.x; w.y = p.y - v.y; }
    else        { w.x = v.x + p.x; w.y = v.y + p.y; }
    float2 p2;
    p2.x = __shfl_xor(w.x, 16);
    p2.y = __shfl_xor(w.y, 16);
    float2 o;
    if (j2 == 0)      { o = make_float2(w.x + p2.x, w.y + p2.y); }
    else if (j2 == 1) { o = make_float2(p2.x - w.x, p2.y - w.y); }
    else if (j2 == 2) { o = INV ? make_float2(w.x - p2.y, w.y + p2.x)
                                : make_float2(w.x + p2.y, w.y - p2.x); }
    else              { o = INV ? make_float2(p2.x + w.y, p2.y - w.x)
                                : make_float2(p2.x - w.y, p2.y + w.x); }
    q[m] = o;
  }
}

// ---------------- K1: row FFT of alpha*z -> A (channel-swizzled store) ----------------
__global__ __launch_bounds__(256) void k1_rowfft(const float* __restrict__ z,
                                                 const float* __restrict__ alpha,
                                                 float2* __restrict__ A) {
  __shared__ float2 x[1088];
  __shared__ float2 tw[768];
  const int t = threadIdx.x;
  const int row = blockIdx.x, nc = blockIdx.y;
  tw_init(tw, t, 256);
  const float al = alpha[nc / 3];
  const float* zr = z + ((size_t)nc * HN + row) * HN;
#pragma unroll
  for (int it = 0; it < 4; ++it) {
    int h = t + (it << 8);
    x[RIDX(h)] = make_float2(zr[h] * al, 0.f);
  }
  fft_row<false>(x, tw, t);
  float2* Ar = A + (size_t)nc * HN * HN + (size_t)row * HN;
  const int X = (row & 63) << 4;
#pragma unroll
  for (int it = 0; it < 4; ++it) {
    int k = t + (it << 8);
    Ar[k ^ X] = x[RIDX(drev(k))];
  }
}

// ---------------- K2: col FFT in-place on A, + FkCFy -> FR ----------------
__global__ __launch_bounds__(1024, 4) void k2_colfft(float2* __restrict__ A,
                                                     const float2* __restrict__ FkCFy) {
  __shared__ float2 ex[8704];
  __shared__ float2 tw[816];
  const int t = threadIdx.x;
  const int c = t & 15, u = t >> 4;
  const int w0 = blockIdx.x << 4;
  const int nc = blockIdx.y;
  const size_t base = (size_t)nc * HN * HN;
  float2 r[16], q[16];
#pragma unroll
  for (int it = 0; it < 16; ++it) {
    int h = u + (it << 6);
    r[it] = A[base + (size_t)h * HN + (aswz(h, w0) + c)];
  }
  tw_init_p(tw, t, 1024);
  __syncthreads();
  colfft16<false>(r, q, ex, tw, u, c);
  const int j2 = u & 3, B = u >> 2;
  const int f = ((j2 & 1) << 1) | (j2 >> 1);
#pragma unroll
  for (int m = 0; m < 16; ++m) {
    int k = (f << 8) | ((m & 3) << 6) | ((m >> 2) << 4) | ((B & 3) << 2) | (B >> 2);
    float2 fy = FkCFy[base + (size_t)k * HN + w0 + c];
    A[base + (size_t)k * HN + (aswz(k, w0) + c)] =
        make_float2(q[m].x + fy.x, q[m].y + fy.y);
  }
}

// ---------------- K3: fused block-means + complex divide -> invWBR ----------------
__global__ __launch_bounds__(256) void k3_reduce(const float2* __restrict__ A,
                                                 const float2* __restrict__ Fk,
                                                 const float2* __restrict__ F2k,
                                                 const float* __restrict__ alpha,
                                                 float2* __restrict__ iw) {
  int idx = blockIdx.x * 256 + threadIdx.x;
  int j = idx & 255, i = (idx >> 8) & 255, nc = idx >> 16;
  size_t base = (size_t)nc * HN * HN;
  float sx = 0.f, sy = 0.f, wx = 0.f, wy = 0.f;
#pragma unroll
  for (int s1 = 0; s1 < 4; ++s1) {
#pragma unroll
    for (int s2 = 0; s2 < 4; ++s2) {
      int h = (s1 << 8) + i, w = (s2 << 8) + j;
      size_t gl = base + (size_t)h * HN + w;
      float2 fr = A[base + (size_t)h * HN + aswz(h, w)];
      float2 fk = Fk[gl];
      float2 f2 = F2k[gl];
      sx += fk.x * fr.x - fk.y * fr.y;
      sy += fk.x * fr.y + fk.y * fr.x;
      wx += f2.x;
      wy += f2.y;
    }
  }
  const float al = alpha[nc / 3];
  float dx = wx * 0.0625f + al, dy = wy * 0.0625f;
  float nx = sx * 0.0625f, ny = sy * 0.0625f;
  float inv = 1.0f / (dx * dx + dy * dy);
  iw[idx] = make_float2((nx * dx + ny * dy) * inv, (ny * dx - nx * dy) * inv);
}

// ---------------- K4: FX = (FR - FkC*invWBR)/alpha, inverse col FFT in-place ----------------
__global__ __launch_bounds__(1024, 4) void k4_colifft(float2* __restrict__ A,
                                                      const float2* __restrict__ FkC,
                                                      const float2* __restrict__ iw,
                                                      const float* __restrict__ alpha) {
  __shared__ float2 ex[8704];
  __shared__ float2 tw[816];
  const int t = threadIdx.x;
  const int c = t & 15, u = t >> 4;
  const int w0 = blockIdx.x << 4;
  const int nc = blockIdx.y;
  const float al = alpha[nc / 3];
  const float ra = 1.0f / al;
  const size_t base = (size_t)nc * HN * HN;
  const int jcol = (w0 + c) & 255;
  const float2* iwp = iw + ((size_t)nc << 16);
  float2 r[16], q[16];
#pragma unroll
  for (int it = 0; it < 16; ++it) {
    int h = u + (it << 6);
    float2 fr = A[base + (size_t)h * HN + (aswz(h, w0) + c)];
    float2 fc = FkC[base + (size_t)h * HN + w0 + c];
    float2 w = iwp[((h & 255) << 8) | jcol];
    float2 p = cmul(fc, w);
    r[it] = make_float2((fr.x - p.x) * ra, (fr.y - p.y) * ra);
  }
  tw_init_p(tw, t, 1024);
  __syncthreads();
  colfft16<true>(r, q, ex, tw, u, c);
  const int j2 = u & 3, B = u >> 2;
  const int f = ((j2 & 1) << 1) | (j2 >> 1);
#pragma unroll
  for (int m = 0; m < 16; ++m) {
    int k = (f << 8) | ((m & 3) << 6) | ((m >> 2) << 4) | ((B & 3) << 2) | (B >> 2);
    A[base + (size_t)k * HN + (aswz(k, w0) + c)] = q[m];
  }
}

// ---------------- K5: inverse row FFT -> real * 1/(H*W) -> out ----------------
__global__ __launch_bounds__(256) void k5_rowifft(const float2* __restrict__ A,
                                                  float* __restrict__ out) {
  __shared__ float2 x[1088];
  __shared__ float2 tw[768];
  const int t = threadIdx.x;
  const int row = blockIdx.x, nc = blockIdx.y;
  tw_init(tw, t, 256);
  const float2* Ar = A + (size_t)nc * HN * HN + (size_t)row * HN;
  const int X = (row & 63) << 4;
#pragma unroll
  for (int it = 0; it < 4; ++it) {
    int h = t + (it << 8);
    x[RIDX(h)] = Ar[h ^ X];
  }
  fft_row<true>(x, tw, t);
  float* outr = out + ((size_t)nc * HN + row) * HN;
  const float sc = 1.0f / (1024.0f * 1024.0f);
#pragma unroll
  for (int it = 0; it < 4; ++it) {
    int k = t + (it << 8);
    outr[k] = x[RIDX(drev(k))].x * sc;
  }
}

extern "C" void kernel_launch(void* const* d_in, const int* in_sizes, int n_in,
                              void* d_out, int out_size, void* d_ws, size_t ws_size,
                              hipStream_t stream) {
  const float*  z      = (const float*)d_in[0];
  const float2* Fk     = (const float2*)d_in[1];
  const float2* FkC    = (const float2*)d_in[2];
  const float2* F2k    = (const float2*)d_in[3];
  const float2* FkCFy  = (const float2*)d_in[4];
  const float*  alpha  = (const float*)d_in[5];
  (void)in_sizes; (void)n_in; (void)out_size; (void)ws_size;

  float2* A  = (float2*)d_ws;                 // 12 x 1024 x 1024 complex (96 MB)
  float2* iw = A + (size_t)NCH * HN * HN;     // 12 x 256 x 256 complex (6 MB)
  float*  out = (float*)d_out;

  k1_rowfft<<<dim3(HN, NCH), dim3(256), 0, stream>>>(z, alpha, A);
  k2_colfft<<<dim3(HN / 16, NCH), dim3(1024), 0, stream>>>(A, FkCFy);
  k3_reduce<<<dim3(NCH * 256), dim3(256), 0, stream>>>(A, Fk, F2k, alpha, iw);
  k4_colifft<<<dim3(HN / 16, NCH), dim3(1024), 0, stream>>>(A, FkC, iw, alpha);
  k5_rowifft<<<dim3(HN, NCH), dim3(256), 0, stream>>>(A, out);
}